// Round 5
// baseline (5698.182 us; speedup 1.0000x reference)
//
#include <hip/hip_runtime.h>

// Bidirectional GRU, persistent-kernel. Round 5.
// B=32, T=1024, D=H=512. 64 WGs = 2 dirs x 32 gate-slices (16 h-cols each).
// Base: r3 structure (proven, 4.48ms). ONE change: tag-embedded h exchange.
//   Each exchange word is u64 {2xfp16 pair | gen tag}, stored with one 8-byte
//   relaxed agent atomic (non-tearing, write-through to LLC). Consumers poll
//   the DATA (16 dwordx4 sc0 sc1 loads in one asm block) until all embedded
//   tags equal the expected generation. This removes the store-ack wait, the
//   flag store, and the flag poll from r3's chain (3 of 4 LLC round-trips).
//   Tag matching also gives the anti-overwrite guarantee: publishing gen s+2
//   into a parity slot requires every WG consumed gen s+1 (induction), and
//   stale tags (prior replay / 0xAA poison) never equal a live gen, so no
//   workspace init is needed at all.
// Barriers are lgkm-only: ih waves never wait on any vmcnt; out stores and
// x prefetch drain off the critical path.

#define T_LEN 1024
#define B_SZ  32
#define D_SZ  512
#define H_SZ  512
#define NWG_DIR 32
#define JW 16
#define NTHR 512

typedef __attribute__((ext_vector_type(8))) _Float16 half8;
typedef __attribute__((ext_vector_type(4))) float f32x4;
typedef __attribute__((ext_vector_type(4))) int int4v;

__device__ __forceinline__ _Float16 f2h(float f) { return (_Float16)f; }
__device__ __forceinline__ float sigm_f(float v) {
  return __builtin_amdgcn_rcpf(1.f + __expf(-v));
}
__device__ __forceinline__ float tanh_f(float v) {
  return 1.f - 2.f * __builtin_amdgcn_rcpf(1.f + __expf(2.f * v));
}
// LDS-only barrier: orders ds ops, does NOT drain vmcnt (x prefetch / out
// stores / h publishes stay in flight).
__device__ __forceinline__ void bar_lgkm() {
  asm volatile("s_waitcnt lgkmcnt(0)\ns_barrier" ::: "memory");
}

__global__ __launch_bounds__(NTHR, 2)
void gru2_persistent(const float* __restrict__ x,
                     const float* __restrict__ wih_fw, const float* __restrict__ whh_fw,
                     const float* __restrict__ bih_fw, const float* __restrict__ bhh_fw,
                     const float* __restrict__ wih_bw, const float* __restrict__ whh_bw,
                     const float* __restrict__ bih_bw, const float* __restrict__ bhh_bw,
                     float* __restrict__ out,
                     unsigned long long* __restrict__ hex64)
{
  __shared__ float Cp[24 * 272];   // 24 C-partial tiles 16x16, +1 col pad
  __shared__ float biasLds[96];

  const int bid  = blockIdx.x;
  const int dir  = bid >> 5;       // 0 = fw, 1 = bw
  const int g    = bid & 31;       // slice: h-cols [g*16, g*16+16)
  const int tid  = threadIdx.x;
  const int wave = tid >> 6;
  const int lane = tid & 63;

  const float* wih = dir ? wih_bw : wih_fw;
  const float* whh = dir ? whh_bw : whh_fw;
  const float* bih = dir ? bih_bw : bih_fw;
  const float* bhh = dir ? bhh_bw : bhh_fw;

  if (tid < 48) {
    int grow = (tid >> 4) * H_SZ + g * JW + (tid & 15);
    biasLds[tid]      = bih[grow];
    biasLds[48 + tid] = bhh[grow];
  }

  const bool isHh = (wave >= 4);
  const int  wv   = wave & 3;
  const int  wm   = wv & 1;        // batch m-tile (16 rows)
  const int  kh   = wv >> 1;       // K half

  // ---- weight B-fragments in registers (layout proven r1-r3) ----
  half8 Bf[3][8];
  {
    const float* W = isHh ? whh : wih;
    #pragma unroll
    for (int gam = 0; gam < 3; ++gam) {
      const int row = gam * H_SZ + g * JW + (lane & 15);
      #pragma unroll
      for (int i = 0; i < 8; ++i) {
        const float* src = W + (size_t)row * D_SZ + (kh * 8 + i) * 32 + ((lane >> 4) << 3);
        float4 v0 = *(const float4*)(src);
        float4 v1 = *(const float4*)(src + 4);
        half8 b;
        b[0]=f2h(v0.x); b[1]=f2h(v0.y); b[2]=f2h(v0.z); b[3]=f2h(v0.w);
        b[4]=f2h(v1.x); b[5]=f2h(v1.y); b[6]=f2h(v1.z); b[7]=f2h(v1.w);
        Bf[gam][i] = b;
      }
    }
  }

  const int arow = wm * 16 + (lane & 15);   // batch row
  const int koff = (lane >> 4) << 3;        // k offset within 32-chunk

  // ---- ih prologue: x(t0) into registers
  float4 xn[16];
  if (!isHh) {
    const int t0 = dir ? (T_LEN - 1) : 0;
    const float* base = x + ((size_t)arow * T_LEN + t0) * D_SZ + kh * 256 + koff;
    #pragma unroll
    for (int i = 0; i < 8; ++i) {
      xn[2*i]   = *(const float4*)(base + i * 32);
      xn[2*i+1] = *(const float4*)(base + i * 32 + 4);
    }
  }
  __syncthreads();

  float hreg = 0.f;
  const int gb = tid >> 4;     // gate batch row
  const int gj = tid & 15;     // gate col within slice
  float* hlast = out + (size_t)B_SZ * T_LEN * (2 * H_SZ) + (size_t)dir * B_SZ * H_SZ;

  for (int s = 0; s < T_LEN; ++s) {
    const int t = dir ? (T_LEN - 1 - s) : s;
    const bool hasNext = (s + 1 < T_LEN);

    f32x4 acc[3] = {{0.f,0.f,0.f,0.f},{0.f,0.f,0.f,0.f},{0.f,0.f,0.f,0.f}};

    if (!isHh) {
      // convert prefetched x(t); issue x(t+1); ih GEMM
      half8 a[8];
      #pragma unroll
      for (int i = 0; i < 8; ++i) {
        float4 u = xn[2*i], w = xn[2*i+1];
        half8 h;
        h[0]=f2h(u.x); h[1]=f2h(u.y); h[2]=f2h(u.z); h[3]=f2h(u.w);
        h[4]=f2h(w.x); h[5]=f2h(w.y); h[6]=f2h(w.z); h[7]=f2h(w.w);
        a[i] = h;
      }
      if (hasNext) {
        const int tn = dir ? (T_LEN - 2 - s) : (s + 1);
        const float* base = x + ((size_t)arow * T_LEN + tn) * D_SZ + kh * 256 + koff;
        #pragma unroll
        for (int i = 0; i < 8; ++i) {
          xn[2*i]   = *(const float4*)(base + i * 32);
          xn[2*i+1] = *(const float4*)(base + i * 32 + 4);
        }
      }
      #pragma unroll
      for (int i = 0; i < 8; ++i)
        #pragma unroll
        for (int gam = 0; gam < 3; ++gam)
          acc[gam] = __builtin_amdgcn_mfma_f32_16x16x32_f16(a[i], Bf[gam][i], acc[gam], 0, 0, 0);
    } else if (s > 0) {
      // ---- tag-polled h(s-1) load: u64 words {pair | gen}, gen == s
      const int geni = s;
      const char* pbase = (const char*)hex64
          + ((((size_t)dir * 2 + ((s - 1) & 1)) * B_SZ + arow) * 256
             + (size_t)kh * 128 + (koff >> 1)) * 8;
      int4v hv[16];
      for (;;) {
        asm volatile(
          "global_load_dwordx4 %0, %16, off sc0 sc1\n\t"
          "global_load_dwordx4 %1, %16, off offset:16 sc0 sc1\n\t"
          "global_load_dwordx4 %2, %16, off offset:128 sc0 sc1\n\t"
          "global_load_dwordx4 %3, %16, off offset:144 sc0 sc1\n\t"
          "global_load_dwordx4 %4, %16, off offset:256 sc0 sc1\n\t"
          "global_load_dwordx4 %5, %16, off offset:272 sc0 sc1\n\t"
          "global_load_dwordx4 %6, %16, off offset:384 sc0 sc1\n\t"
          "global_load_dwordx4 %7, %16, off offset:400 sc0 sc1\n\t"
          "global_load_dwordx4 %8, %16, off offset:512 sc0 sc1\n\t"
          "global_load_dwordx4 %9, %16, off offset:528 sc0 sc1\n\t"
          "global_load_dwordx4 %10, %16, off offset:640 sc0 sc1\n\t"
          "global_load_dwordx4 %11, %16, off offset:656 sc0 sc1\n\t"
          "global_load_dwordx4 %12, %16, off offset:768 sc0 sc1\n\t"
          "global_load_dwordx4 %13, %16, off offset:784 sc0 sc1\n\t"
          "global_load_dwordx4 %14, %16, off offset:896 sc0 sc1\n\t"
          "global_load_dwordx4 %15, %16, off offset:912 sc0 sc1\n\t"
          "s_waitcnt vmcnt(0)"
          : "=&v"(hv[0]), "=&v"(hv[1]), "=&v"(hv[2]), "=&v"(hv[3]),
            "=&v"(hv[4]), "=&v"(hv[5]), "=&v"(hv[6]), "=&v"(hv[7]),
            "=&v"(hv[8]), "=&v"(hv[9]), "=&v"(hv[10]), "=&v"(hv[11]),
            "=&v"(hv[12]), "=&v"(hv[13]), "=&v"(hv[14]), "=&v"(hv[15])
          : "v"(pbase)
          : "memory");
        int bad = 0;
        #pragma unroll
        for (int k2 = 0; k2 < 16; ++k2)
          bad |= (hv[k2][1] ^ geni) | (hv[k2][3] ^ geni);
        if (__all(bad == 0)) break;
      }
      // repack pairs -> A-fragments; hh GEMM
      #pragma unroll
      for (int i = 0; i < 8; ++i) {
        int4v w;
        w[0] = hv[2*i][0];   w[1] = hv[2*i][2];
        w[2] = hv[2*i+1][0]; w[3] = hv[2*i+1][2];
        half8 a = __builtin_bit_cast(half8, w);
        #pragma unroll
        for (int gam = 0; gam < 3; ++gam)
          acc[gam] = __builtin_amdgcn_mfma_f32_16x16x32_f16(a, Bf[gam][i], acc[gam], 0, 0, 0);
      }
    }
    // (hh at s==0: acc stays zero, h0 = 0)

    // ---- write C-partials
    {
      const int src = isHh ? 1 : 0;
      #pragma unroll
      for (int gam = 0; gam < 3; ++gam) {
        float* cp = Cp + (size_t)(((src*2 + kh)*3 + gam)*2 + wm) * 272
                       + ((lane >> 4) << 2) * 17 + (lane & 15);
        #pragma unroll
        for (int vv2 = 0; vv2 < 4; ++vv2) cp[vv2 * 17] = acc[gam][vv2];
      }
    }
    bar_lgkm();   // B1: Cp ready (lgkm only)

    // ---- gates (all 512 threads), publish h(s) with embedded gen s+1
    {
      const int mb = gb >> 4, rb = gb & 15;
      float sih[3], shh[3];
      #pragma unroll
      for (int gam = 0; gam < 3; ++gam) {
        float aih = 0.f, ahh = 0.f;
        #pragma unroll
        for (int q = 0; q < 2; ++q) {
          aih += Cp[(size_t)(((0*2+q)*3+gam)*2 + mb) * 272 + rb * 17 + gj];
          ahh += Cp[(size_t)(((1*2+q)*3+gam)*2 + mb) * 272 + rb * 17 + gj];
        }
        sih[gam] = aih + biasLds[gam * 16 + gj];
        shh[gam] = ahh + biasLds[48 + gam * 16 + gj];
      }
      const float r = sigm_f(sih[0] + shh[0]);
      const float z = sigm_f(sih[1] + shh[1]);
      const float n = tanh_f(sih[2] + r * shh[2]);
      const float hn = (1.f - z) * n + z * hreg;
      hreg = hn;

      // publish FIRST (critical path), then out stores (slack)
      const float hother = __shfl_xor(hn, 1);
      if ((gj & 1) == 0) {
        union { unsigned u; _Float16 h[2]; } pr;
        pr.h[0] = f2h(hn); pr.h[1] = f2h(hother);
        const unsigned long long pk =
            (unsigned long long)pr.u | ((unsigned long long)(unsigned)(s + 1) << 32);
        unsigned long long* hp = hex64
            + ((size_t)dir * 2 + (s & 1)) * (B_SZ * 256)
            + (size_t)gb * 256 + (g * 8 + (gj >> 1));
        __hip_atomic_store(hp, pk, __ATOMIC_RELAXED, __HIP_MEMORY_SCOPE_AGENT);
      }
      out[((size_t)gb * T_LEN + t) * (2 * H_SZ) + dir * H_SZ + g * JW + gj] = hn;
      if (s == T_LEN - 1) hlast[gb * H_SZ + g * JW + gj] = hn;
    }
    bar_lgkm();   // B2: Cp reads done before next step overwrites
  }
}

extern "C" void kernel_launch(void* const* d_in, const int* in_sizes, int n_in,
                              void* d_out, int out_size, void* d_ws, size_t ws_size,
                              hipStream_t stream) {
  const float* x      = (const float*)d_in[0];
  const float* wih_fw = (const float*)d_in[1];
  const float* whh_fw = (const float*)d_in[2];
  const float* bih_fw = (const float*)d_in[3];
  const float* bhh_fw = (const float*)d_in[4];
  const float* wih_bw = (const float*)d_in[5];
  const float* whh_bw = (const float*)d_in[6];
  const float* bih_bw = (const float*)d_in[7];
  const float* bhh_bw = (const float*)d_in[8];
  float* out = (float*)d_out;

  // ws: hex64 [2 dir][2 parity][32 rows][256 pairs] u64 = 512 KB.
  // No initialization needed: stale/poison tags never match a live gen.
  const size_t HEX_BYTES = (size_t)2 * 2 * B_SZ * 256 * sizeof(unsigned long long);
  if (ws_size < HEX_BYTES) return;

  unsigned long long* hex64 = (unsigned long long*)d_ws;

  gru2_persistent<<<dim3(64), dim3(NTHR), 0, stream>>>(
      x, wih_fw, whh_fw, bih_fw, bhh_fw, wih_bw, whh_bw, bih_bw, bhh_bw,
      out, hex64);
}

// Round 7
// 4860.690 us; speedup vs baseline: 1.1723x; 1.1723x over previous
//
#include <hip/hip_runtime.h>

// Bidirectional GRU, persistent-kernel. Round 7.
// Base: r3 protocol (PROVEN: grid 64, agent-relaxed sc0sc1 comm, flag+payload).
// The r4/r6 XCD-scope experiment is abandoned (2 hangs, no data).
// r7 = r3 + chain slimming only:
//  - lgkm-only barriers (x prefetch / out stores never drained on the chain)
//  - h publish by WAVE 4 ALONE via 1KB LDS hop: gates ds_write packed pairs ->
//    B2(lgkm) -> wave4 reads hLds, 2 u64 agent stores/lane, OWN vmcnt(0)
//    (h acks only), lane0 posts monotonic flag. No full-block vmcnt drain,
//    no cross-wave tokens.
//  - out/hlast stores: ih waves during gate phase, hh waves after the flag
//    (never gate the flag).
//  - fast sigmoid/tanh (no libcalls on the chain).
// Liveness: only spin is the r3-proven intrinsic flag poll; wave4's publish is
// unconditionally reached; flags re-zeroed each replay by captured memset;
// payload buffer is flag-gated (no init needed).

#define T_LEN 1024
#define B_SZ  32
#define D_SZ  512
#define H_SZ  512
#define NWG_DIR 32
#define JW 16
#define NTHR 512

typedef __attribute__((ext_vector_type(8))) _Float16 half8;
typedef __attribute__((ext_vector_type(4))) float f32x4;
typedef __attribute__((ext_vector_type(4))) int int4v;

__device__ __forceinline__ _Float16 f2h(float f) { return (_Float16)f; }
__device__ __forceinline__ float sigm_f(float v) {
  return __builtin_amdgcn_rcpf(1.f + __expf(-v));
}
__device__ __forceinline__ float tanh_f(float v) {
  return 1.f - 2.f * __builtin_amdgcn_rcpf(1.f + __expf(2.f * v));
}
// LDS-only barrier: orders ds ops; does NOT drain vmcnt.
__device__ __forceinline__ void bar_lgkm() {
  asm volatile("s_waitcnt lgkmcnt(0)\ns_barrier" ::: "memory");
}

__global__ __launch_bounds__(NTHR, 2)
void gru2_persistent(const float* __restrict__ x,
                     const float* __restrict__ wih_fw, const float* __restrict__ whh_fw,
                     const float* __restrict__ bih_fw, const float* __restrict__ bhh_fw,
                     const float* __restrict__ wih_bw, const float* __restrict__ whh_bw,
                     const float* __restrict__ bih_bw, const float* __restrict__ bhh_bw,
                     float* __restrict__ out,
                     unsigned long long* __restrict__ hex64,
                     unsigned* __restrict__ flags)
{
  __shared__ float Cp[24 * 272];            // 24 C-partial tiles 16x16, +1 col pad
  __shared__ float biasLds[96];
  __shared__ unsigned long long hLds64[B_SZ * 4];  // 32 rows x 8 packed-pair u32
  unsigned* hLds = (unsigned*)hLds64;

  const int bid  = blockIdx.x;
  const int dir  = bid >> 5;      // 0 = fw, 1 = bw
  const int g    = bid & 31;      // slice: h-cols [g*16, g*16+16)
  const int tid  = threadIdx.x;
  const int wave = tid >> 6;
  const int lane = tid & 63;

  const float* wih = dir ? wih_bw : wih_fw;
  const float* whh = dir ? whh_bw : whh_fw;
  const float* bih = dir ? bih_bw : bih_fw;
  const float* bhh = dir ? bhh_bw : bhh_fw;

  if (tid < 48) {
    int grow = (tid >> 4) * H_SZ + g * JW + (tid & 15);
    biasLds[tid]      = bih[grow];
    biasLds[48 + tid] = bhh[grow];
  }

  const bool isHh = (wave >= 4);
  const int  wv   = wave & 3;
  const int  wm   = wv & 1;       // batch m-tile (16 rows)
  const int  kh   = wv >> 1;      // K half

  // ---- weight B-fragments in registers (layout proven r1-r5) ----
  half8 Bf[3][8];
  {
    const float* W = isHh ? whh : wih;
    #pragma unroll
    for (int gam = 0; gam < 3; ++gam) {
      const int row = gam * H_SZ + g * JW + (lane & 15);
      #pragma unroll
      for (int i = 0; i < 8; ++i) {
        const float* src = W + (size_t)row * D_SZ + (kh * 8 + i) * 32 + ((lane >> 4) << 3);
        float4 v0 = *(const float4*)(src);
        float4 v1 = *(const float4*)(src + 4);
        half8 b;
        b[0]=f2h(v0.x); b[1]=f2h(v0.y); b[2]=f2h(v0.z); b[3]=f2h(v0.w);
        b[4]=f2h(v1.x); b[5]=f2h(v1.y); b[6]=f2h(v1.z); b[7]=f2h(v1.w);
        Bf[gam][i] = b;
      }
    }
  }

  const int arow = wm * 16 + (lane & 15);   // batch row
  const int koff = (lane >> 4) << 3;        // k offset within 32-chunk

  // ---- ih prologue: x(t0) into registers
  float4 xn[16];
  if (!isHh) {
    const int t0 = dir ? (T_LEN - 1) : 0;
    const float* base = x + ((size_t)arow * T_LEN + t0) * D_SZ + kh * 256 + koff;
    #pragma unroll
    for (int i = 0; i < 8; ++i) {
      xn[2*i]   = *(const float4*)(base + i * 32);
      xn[2*i+1] = *(const float4*)(base + i * 32 + 4);
    }
  }
  __syncthreads();

  float hreg = 0.f;
  const int gb = tid >> 4;       // gate batch row
  const int gj = tid & 15;       // gate col within slice
  float* hlast = out + (size_t)B_SZ * T_LEN * (2 * H_SZ) + (size_t)dir * B_SZ * H_SZ;
  const unsigned* flbase = flags + (size_t)dir * NWG_DIR;

  for (int s = 0; s < T_LEN; ++s) {
    const int t = dir ? (T_LEN - 1 - s) : s;
    const bool hasNext = (s + 1 < T_LEN);

    f32x4 acc[3] = {{0.f,0.f,0.f,0.f},{0.f,0.f,0.f,0.f},{0.f,0.f,0.f,0.f}};

    if (!isHh) {
      // convert prefetched x(t); issue x(t+1); ih GEMM
      half8 a[8];
      #pragma unroll
      for (int i = 0; i < 8; ++i) {
        float4 u = xn[2*i], w = xn[2*i+1];
        half8 h;
        h[0]=f2h(u.x); h[1]=f2h(u.y); h[2]=f2h(u.z); h[3]=f2h(u.w);
        h[4]=f2h(w.x); h[5]=f2h(w.y); h[6]=f2h(w.z); h[7]=f2h(w.w);
        a[i] = h;
      }
      if (hasNext) {
        const int tn = dir ? (T_LEN - 2 - s) : (s + 1);
        const float* base = x + ((size_t)arow * T_LEN + tn) * D_SZ + kh * 256 + koff;
        #pragma unroll
        for (int i = 0; i < 8; ++i) {
          xn[2*i]   = *(const float4*)(base + i * 32);
          xn[2*i+1] = *(const float4*)(base + i * 32 + 4);
        }
      }
      #pragma unroll
      for (int i = 0; i < 8; ++i)
        #pragma unroll
        for (int gam = 0; gam < 3; ++gam)
          acc[gam] = __builtin_amdgcn_mfma_f32_16x16x32_f16(a[i], Bf[gam][i], acc[gam], 0, 0, 0);
    } else if (s > 0) {
      // ---- flag poll (intrinsic, proven r3): all 32 producers at gen >= s
      for (;;) {
        unsigned v = (lane < NWG_DIR)
            ? __hip_atomic_load(&flbase[lane], __ATOMIC_RELAXED,
                                __HIP_MEMORY_SCOPE_AGENT)
            : 0xFFFFFFFFu;
        if (__all(v >= (unsigned)s)) break;
      }
      // ---- load h(s-1) payload exactly once (early-clobber asm, proven r5)
      const char* p0 = (const char*)hex64
          + (((size_t)dir * 2 + ((s - 1) & 1)) * (B_SZ * 128)) * 8
          + (size_t)arow * 1024 + (size_t)kh * 512 + (size_t)koff * 2;
      int4v hv[8];
      asm volatile(
        "global_load_dwordx4 %0, %8, off sc0 sc1\n\t"
        "global_load_dwordx4 %1, %8, off offset:64 sc0 sc1\n\t"
        "global_load_dwordx4 %2, %8, off offset:128 sc0 sc1\n\t"
        "global_load_dwordx4 %3, %8, off offset:192 sc0 sc1\n\t"
        "global_load_dwordx4 %4, %8, off offset:256 sc0 sc1\n\t"
        "global_load_dwordx4 %5, %8, off offset:320 sc0 sc1\n\t"
        "global_load_dwordx4 %6, %8, off offset:384 sc0 sc1\n\t"
        "global_load_dwordx4 %7, %8, off offset:448 sc0 sc1\n\t"
        "s_waitcnt vmcnt(0)"
        : "=&v"(hv[0]), "=&v"(hv[1]), "=&v"(hv[2]), "=&v"(hv[3]),
          "=&v"(hv[4]), "=&v"(hv[5]), "=&v"(hv[6]), "=&v"(hv[7])
        : "v"(p0) : "memory");
      __builtin_amdgcn_sched_barrier(0);
      #pragma unroll
      for (int i = 0; i < 8; ++i) {
        half8 a = __builtin_bit_cast(half8, hv[i]);
        #pragma unroll
        for (int gam = 0; gam < 3; ++gam)
          acc[gam] = __builtin_amdgcn_mfma_f32_16x16x32_f16(a, Bf[gam][i], acc[gam], 0, 0, 0);
      }
    }
    // hh at s==0: acc stays zero (h0 = 0)

    // ---- write C-partials
    {
      const int src = isHh ? 1 : 0;
      #pragma unroll
      for (int gam = 0; gam < 3; ++gam) {
        float* cp = Cp + (size_t)(((src*2 + kh)*3 + gam)*2 + wm) * 272
                       + ((lane >> 4) << 2) * 17 + (lane & 15);
        #pragma unroll
        for (int vv2 = 0; vv2 < 4; ++vv2) cp[vv2 * 17] = acc[gam][vv2];
      }
    }
    bar_lgkm();   // B1: Cp ready (lgkm only; x prefetch stays in flight)

    // ---- gates (all 512 threads): compute h(s), stage pairs in LDS
    float hnS;
    {
      const int mb = gb >> 4, rb = gb & 15;
      float sih[3], shh[3];
      #pragma unroll
      for (int gam = 0; gam < 3; ++gam) {
        float aih = 0.f, ahh = 0.f;
        #pragma unroll
        for (int q = 0; q < 2; ++q) {
          aih += Cp[(size_t)(((0*2+q)*3+gam)*2 + mb) * 272 + rb * 17 + gj];
          ahh += Cp[(size_t)(((1*2+q)*3+gam)*2 + mb) * 272 + rb * 17 + gj];
        }
        sih[gam] = aih + biasLds[gam * 16 + gj];
        shh[gam] = ahh + biasLds[48 + gam * 16 + gj];
      }
      const float r = sigm_f(sih[0] + shh[0]);
      const float z = sigm_f(sih[1] + shh[1]);
      const float n = tanh_f(sih[2] + r * shh[2]);
      const float hn = (1.f - z) * n + z * hreg;
      hreg = hn;
      hnS = hn;

      const float hother = __shfl_xor(hn, 1);
      if ((gj & 1) == 0) {
        union { unsigned u; _Float16 h[2]; } pr;
        pr.h[0] = f2h(hn); pr.h[1] = f2h(hother);
        hLds[gb * 8 + (gj >> 1)] = pr.u;     // ds_write (ordered by B2)
      }
      if (!isHh) {
        // ih waves: off-chain, store out now (plain cached, never drained)
        out[((size_t)gb * T_LEN + t) * (2 * H_SZ) + dir * H_SZ + g * JW + gj] = hn;
        if (s == T_LEN - 1) hlast[gb * H_SZ + g * JW + gj] = hn;
      }
    }
    bar_lgkm();   // B2: hLds visible; Cp reads done

    // ---- publish: wave 4 ALONE stores the WG's 128 u64 and posts the flag
    if (wave == 4) {
      const size_t pb = ((size_t)dir * 2 + (s & 1)) * (B_SZ * 128);
      #pragma unroll
      for (int i = 0; i < 2; ++i) {
        const int id2 = i * 64 + lane;       // 0..127
        const int gbp = id2 >> 2, jp = id2 & 3;
        __hip_atomic_store(&hex64[pb + (size_t)gbp * 128 + g * 4 + jp],
                           hLds64[gbp * 4 + jp],
                           __ATOMIC_RELAXED, __HIP_MEMORY_SCOPE_AGENT);
      }
      asm volatile("s_waitcnt vmcnt(0)" ::: "memory");  // h acks only (this wave)
      if (lane == 0)
        __hip_atomic_store((unsigned*)&flags[(size_t)dir * NWG_DIR + g],
                           (unsigned)(s + 1),
                           __ATOMIC_RELAXED, __HIP_MEMORY_SCOPE_AGENT);
    }
    if (isHh) {
      // hh waves: deferred out stores (after flag; never gate it)
      out[((size_t)gb * T_LEN + t) * (2 * H_SZ) + dir * H_SZ + g * JW + gj] = hnS;
      if (s == T_LEN - 1) hlast[gb * H_SZ + g * JW + gj] = hnS;
    }
  }
}

extern "C" void kernel_launch(void* const* d_in, const int* in_sizes, int n_in,
                              void* d_out, int out_size, void* d_ws, size_t ws_size,
                              hipStream_t stream) {
  const float* x      = (const float*)d_in[0];
  const float* wih_fw = (const float*)d_in[1];
  const float* whh_fw = (const float*)d_in[2];
  const float* bih_fw = (const float*)d_in[3];
  const float* bhh_fw = (const float*)d_in[4];
  const float* wih_bw = (const float*)d_in[5];
  const float* whh_bw = (const float*)d_in[6];
  const float* bih_bw = (const float*)d_in[7];
  const float* bhh_bw = (const float*)d_in[8];
  float* out = (float*)d_out;

  // ws: flags u32[2][32] = 256 B (zeroed each call, captured in graph);
  //     hex64 [2 dir][2 parity][32 rows][128 u64] = 128 KB (flag-gated, no init).
  const size_t FLAGS_BYTES = 256;
  const size_t HEX_BYTES   = (size_t)2 * 2 * B_SZ * 128 * sizeof(unsigned long long);
  if (ws_size < FLAGS_BYTES + HEX_BYTES) return;

  unsigned* flags = (unsigned*)d_ws;
  unsigned long long* hex64 = (unsigned long long*)((char*)d_ws + FLAGS_BYTES);

  hipMemsetAsync(flags, 0, FLAGS_BYTES, stream);
  gru2_persistent<<<dim3(64), dim3(NTHR), 0, stream>>>(
      x, wih_fw, whh_fw, bih_fw, bhh_fw, wih_bw, whh_bw, bih_bw, bhh_bw,
      out, hex64, flags);
}

// Round 8
// 4777.883 us; speedup vs baseline: 1.1926x; 1.0173x over previous
//
#include <hip/hip_runtime.h>

// Bidirectional GRU, persistent-kernel. Round 8.
// Base: r3 protocol (grid 64, agent-relaxed comm, flag then payload, proven).
// r8 attacks CONTENTION + REQUEST COUNT, the revised theory for the ~10.5k
// cy/step floor (r7 regression traced to sleepless 256-wave flag hammering):
//  1) ONE polling wave per WG (wave 4) with s_sleep backoff; waves 5-7 wait
//     on an LDS token (no fabric traffic). ~8x less load on the flag lines.
//  2) Coalesced exchange layout [chunk=k/8][row][8 fp16]: producers pack 8
//     halves via 3 shfl_xor levels -> 8x16B stores per wave (was 32x4B);
//     consumers read 256B-contiguous segments (was 64 scattered 16B/WG-wave).
//  3) Publish straight from gate registers (no LDS hop); per-wave vmcnt(0)
//     acks h only (out stores deferred until after the flag).
// Liveness: flag poll = r3-proven intrinsic loop; LDS token written
// unconditionally by wave4 each step; flags zeroed per replay by captured
// memset; payload is flag-gated (no init; parity-2 anti-overwrite induction
// re-verified: WG A overwrites parity p at step s+1 only after all flags>=s+1,
// posted after every WG finished READING parity p at step s).

#define T_LEN 1024
#define B_SZ  32
#define D_SZ  512
#define H_SZ  512
#define NWG_DIR 32
#define JW 16
#define NTHR 512

typedef __attribute__((ext_vector_type(8))) _Float16 half8;
typedef __attribute__((ext_vector_type(4))) float f32x4;
typedef __attribute__((ext_vector_type(4))) int int4v;

__device__ __forceinline__ _Float16 f2h(float f) { return (_Float16)f; }
__device__ __forceinline__ float sigm_f(float v) {
  return __builtin_amdgcn_rcpf(1.f + __expf(-v));
}
__device__ __forceinline__ float tanh_f(float v) {
  return 1.f - 2.f * __builtin_amdgcn_rcpf(1.f + __expf(2.f * v));
}
// LDS-only barrier: orders ds ops; does NOT drain vmcnt.
__device__ __forceinline__ void bar_lgkm() {
  asm volatile("s_waitcnt lgkmcnt(0)\ns_barrier" ::: "memory");
}

__global__ __launch_bounds__(NTHR, 2)
void gru2_persistent(const float* __restrict__ x,
                     const float* __restrict__ wih_fw, const float* __restrict__ whh_fw,
                     const float* __restrict__ bih_fw, const float* __restrict__ bhh_fw,
                     const float* __restrict__ wih_bw, const float* __restrict__ whh_bw,
                     const float* __restrict__ bih_bw, const float* __restrict__ bhh_bw,
                     float* __restrict__ out,
                     char* __restrict__ hexF,
                     unsigned* __restrict__ flags)
{
  __shared__ float Cp[24 * 272];   // 24 C-partial tiles 16x16, +1 col pad
  __shared__ float biasLds[96];
  __shared__ int tok;              // flag-ready token from wave4 to waves 5-7

  const int bid  = blockIdx.x;
  const int dir  = bid >> 5;      // 0 = fw, 1 = bw
  const int g    = bid & 31;      // slice: h-cols [g*16, g*16+16)
  const int tid  = threadIdx.x;
  const int wave = tid >> 6;
  const int lane = tid & 63;

  const float* wih = dir ? wih_bw : wih_fw;
  const float* whh = dir ? whh_bw : whh_fw;
  const float* bih = dir ? bih_bw : bih_fw;
  const float* bhh = dir ? bhh_bw : bhh_fw;

  if (tid == 0) tok = 0;
  if (tid < 48) {
    int grow = (tid >> 4) * H_SZ + g * JW + (tid & 15);
    biasLds[tid]      = bih[grow];
    biasLds[48 + tid] = bhh[grow];
  }

  const bool isHh = (wave >= 4);
  const int  wv   = wave & 3;
  const int  wm   = wv & 1;       // batch m-tile (16 rows)
  const int  kh   = wv >> 1;      // K half

  // ---- weight B-fragments in registers (layout proven r1-r7) ----
  half8 Bf[3][8];
  {
    const float* W = isHh ? whh : wih;
    #pragma unroll
    for (int gam = 0; gam < 3; ++gam) {
      const int row = gam * H_SZ + g * JW + (lane & 15);
      #pragma unroll
      for (int i = 0; i < 8; ++i) {
        const float* src = W + (size_t)row * D_SZ + (kh * 8 + i) * 32 + ((lane >> 4) << 3);
        float4 v0 = *(const float4*)(src);
        float4 v1 = *(const float4*)(src + 4);
        half8 b;
        b[0]=f2h(v0.x); b[1]=f2h(v0.y); b[2]=f2h(v0.z); b[3]=f2h(v0.w);
        b[4]=f2h(v1.x); b[5]=f2h(v1.y); b[6]=f2h(v1.z); b[7]=f2h(v1.w);
        Bf[gam][i] = b;
      }
    }
  }

  const int arow = wm * 16 + (lane & 15);   // batch row
  const int koff = (lane >> 4) << 3;        // k offset within 32-chunk

  // ---- ih prologue: x(t0) into registers
  float4 xn[16];
  if (!isHh) {
    const int t0 = dir ? (T_LEN - 1) : 0;
    const float* base = x + ((size_t)arow * T_LEN + t0) * D_SZ + kh * 256 + koff;
    #pragma unroll
    for (int i = 0; i < 8; ++i) {
      xn[2*i]   = *(const float4*)(base + i * 32);
      xn[2*i+1] = *(const float4*)(base + i * 32 + 4);
    }
  }
  __syncthreads();   // also publishes tok=0

  float hreg = 0.f;
  const int gb = tid >> 4;       // gate batch row
  const int gj = tid & 15;       // gate col within slice
  float* hlast = out + (size_t)B_SZ * T_LEN * (2 * H_SZ) + (size_t)dir * B_SZ * H_SZ;
  const unsigned* flbase = flags + (size_t)dir * NWG_DIR;
  // exchange: [dir][parity] blocks of 32KB = [64 chunks][32 rows][16B]
  char* const exbase = hexF + (size_t)dir * 2 * 32768;

  for (int s = 0; s < T_LEN; ++s) {
    const int t = dir ? (T_LEN - 1 - s) : s;
    const bool hasNext = (s + 1 < T_LEN);

    f32x4 acc[3] = {{0.f,0.f,0.f,0.f},{0.f,0.f,0.f,0.f},{0.f,0.f,0.f,0.f}};

    if (!isHh) {
      // convert prefetched x(t); issue x(t+1); ih GEMM
      half8 a[8];
      #pragma unroll
      for (int i = 0; i < 8; ++i) {
        float4 u = xn[2*i], w = xn[2*i+1];
        half8 h;
        h[0]=f2h(u.x); h[1]=f2h(u.y); h[2]=f2h(u.z); h[3]=f2h(u.w);
        h[4]=f2h(w.x); h[5]=f2h(w.y); h[6]=f2h(w.z); h[7]=f2h(w.w);
        a[i] = h;
      }
      if (hasNext) {
        const int tn = dir ? (T_LEN - 2 - s) : (s + 1);
        const float* base = x + ((size_t)arow * T_LEN + tn) * D_SZ + kh * 256 + koff;
        #pragma unroll
        for (int i = 0; i < 8; ++i) {
          xn[2*i]   = *(const float4*)(base + i * 32);
          xn[2*i+1] = *(const float4*)(base + i * 32 + 4);
        }
      }
      #pragma unroll
      for (int i = 0; i < 8; ++i)
        #pragma unroll
        for (int gam = 0; gam < 3; ++gam)
          acc[gam] = __builtin_amdgcn_mfma_f32_16x16x32_f16(a[i], Bf[gam][i], acc[gam], 0, 0, 0);
    } else if (s > 0) {
      // ---- wait for h(s-1): wave4 polls flags (with backoff), others take token
      if (wave == 4) {
        for (;;) {
          unsigned v = (lane < NWG_DIR)
              ? __hip_atomic_load(&flbase[lane], __ATOMIC_RELAXED,
                                  __HIP_MEMORY_SCOPE_AGENT)
              : 0xFFFFFFFFu;
          if (__all(v >= (unsigned)s)) break;
          __builtin_amdgcn_s_sleep(1);
        }
        if (lane == 0) *((volatile int*)&tok) = s;
      } else {
        while (*((volatile int*)&tok) < s) __builtin_amdgcn_s_sleep(1);
      }
      // ---- load h(s-1) payload once (coalesced 16B/lane x 8 chunks)
      const char* pb = exbase + (size_t)((s - 1) & 1) * 32768;
      const char* a0 = pb + ((size_t)(kh * 32 + (lane >> 4)) * 512) + (size_t)arow * 16;
      int4v hv[8];
      #pragma unroll
      for (int i = 0; i < 8; ++i)
        asm volatile("global_load_dwordx4 %0, %1, off sc0 sc1"
                     : "=&v"(hv[i]) : "v"(a0 + (size_t)i * 2048));
      asm volatile("s_waitcnt vmcnt(0)" ::: "memory");
      __builtin_amdgcn_sched_barrier(0);
      #pragma unroll
      for (int i = 0; i < 8; ++i) {
        half8 a = __builtin_bit_cast(half8, hv[i]);
        #pragma unroll
        for (int gam = 0; gam < 3; ++gam)
          acc[gam] = __builtin_amdgcn_mfma_f32_16x16x32_f16(a, Bf[gam][i], acc[gam], 0, 0, 0);
      }
    }
    // hh at s==0: acc stays zero (h0 = 0)

    // ---- write C-partials
    {
      const int src = isHh ? 1 : 0;
      #pragma unroll
      for (int gam = 0; gam < 3; ++gam) {
        float* cp = Cp + (size_t)(((src*2 + kh)*3 + gam)*2 + wm) * 272
                       + ((lane >> 4) << 2) * 17 + (lane & 15);
        #pragma unroll
        for (int vv2 = 0; vv2 < 4; ++vv2) cp[vv2 * 17] = acc[gam][vv2];
      }
    }
    bar_lgkm();   // B1: Cp ready (x prefetch stays in flight)

    // ---- gates (all 512 threads): compute h(s), pack, publish coalesced
    float hnS;
    {
      const int mb = gb >> 4, rb = gb & 15;
      float sih[3], shh[3];
      #pragma unroll
      for (int gam = 0; gam < 3; ++gam) {
        float aih = 0.f, ahh = 0.f;
        #pragma unroll
        for (int q = 0; q < 2; ++q) {
          aih += Cp[(size_t)(((0*2+q)*3+gam)*2 + mb) * 272 + rb * 17 + gj];
          ahh += Cp[(size_t)(((1*2+q)*3+gam)*2 + mb) * 272 + rb * 17 + gj];
        }
        sih[gam] = aih + biasLds[gam * 16 + gj];
        shh[gam] = ahh + biasLds[48 + gam * 16 + gj];
      }
      const float r = sigm_f(sih[0] + shh[0]);
      const float z = sigm_f(sih[1] + shh[1]);
      const float n = tanh_f(sih[2] + r * shh[2]);
      const float hn = (1.f - z) * n + z * hreg;
      hreg = hn;
      hnS = hn;

      // pack 8 halves/16B via 3 shfl_xor levels; lanes with (lane&7)==0 store
      const unsigned hu = (unsigned)__builtin_bit_cast(unsigned short, f2h(hn));
      unsigned v0 = hu | ((unsigned)__shfl_xor((int)hu, 1) << 16);
      unsigned v1 = (unsigned)__shfl_xor((int)v0, 2);
      unsigned v2 = (unsigned)__shfl_xor((int)v0, 4);
      unsigned v3 = (unsigned)__shfl_xor((int)v1, 4);
      if ((lane & 7) == 0) {
        int4v pk; pk[0] = (int)v0; pk[1] = (int)v1; pk[2] = (int)v2; pk[3] = (int)v3;
        char* dst = exbase + (size_t)(s & 1) * 32768
                  + (size_t)(2 * g + ((lane >> 3) & 1)) * 512
                  + (size_t)gb * 16;
        asm volatile("global_store_dwordx4 %0, %1, off sc0 sc1"
                     :: "v"(dst), "v"(pk) : "memory");
      }
    }
    // B2: every wave acks its h stores at the coherence point, then barrier
    asm volatile("s_waitcnt vmcnt(0) lgkmcnt(0)\ns_barrier" ::: "memory");
    if (tid == 0)
      __hip_atomic_store((unsigned*)&flags[(size_t)dir * NWG_DIR + g],
                         (unsigned)(s + 1),
                         __ATOMIC_RELAXED, __HIP_MEMORY_SCOPE_AGENT);
    // deferred out stores (never gate the flag)
    out[((size_t)gb * T_LEN + t) * (2 * H_SZ) + dir * H_SZ + g * JW + gj] = hnS;
    if (s == T_LEN - 1) hlast[gb * H_SZ + g * JW + gj] = hnS;
  }
}

extern "C" void kernel_launch(void* const* d_in, const int* in_sizes, int n_in,
                              void* d_out, int out_size, void* d_ws, size_t ws_size,
                              hipStream_t stream) {
  const float* x      = (const float*)d_in[0];
  const float* wih_fw = (const float*)d_in[1];
  const float* whh_fw = (const float*)d_in[2];
  const float* bih_fw = (const float*)d_in[3];
  const float* bhh_fw = (const float*)d_in[4];
  const float* wih_bw = (const float*)d_in[5];
  const float* whh_bw = (const float*)d_in[6];
  const float* bih_bw = (const float*)d_in[7];
  const float* bhh_bw = (const float*)d_in[8];
  float* out = (float*)d_out;

  // ws: flags u32[2][32] = 256 B (zeroed per replay, captured);
  //     hexF [2 dir][2 parity][64 chunk][32 row][16B] = 128 KB (flag-gated).
  const size_t FLAGS_BYTES = 256;
  const size_t HEX_BYTES   = (size_t)2 * 2 * 64 * 32 * 16;
  if (ws_size < FLAGS_BYTES + HEX_BYTES) return;

  unsigned* flags = (unsigned*)d_ws;
  char* hexF = (char*)d_ws + FLAGS_BYTES;

  hipMemsetAsync(flags, 0, FLAGS_BYTES, stream);
  gru2_persistent<<<dim3(64), dim3(NTHR), 0, stream>>>(
      x, wih_fw, whh_fw, bih_fw, bhh_fw, wih_bw, whh_bw, bih_bw, bhh_bw,
      out, hexF, flags);
}